// Round 2
// baseline (653.283 us; speedup 1.0000x reference)
//
#include <hip/hip_runtime.h>
#include <hip/hip_bf16.h>
#include <stdint.h>

typedef __attribute__((ext_vector_type(8))) short s16x8;    // bf16 MFMA A/B frag (4 VGPRs)
typedef __attribute__((ext_vector_type(4))) float f32x4;    // MFMA C/D frag
typedef __attribute__((ext_vector_type(8))) unsigned short us8;
typedef __attribute__((ext_vector_type(4))) unsigned short us4;

// ---- bf16 round-to-nearest-even (inputs are finite normals) ----
__device__ inline unsigned short bf_rne(float f) {
    union { float f; uint32_t u; } v; v.f = f;
    uint32_t u = v.u;
    u += 0x7FFFu + ((u >> 16) & 1u);
    return (unsigned short)(u >> 16);
}

// async global->LDS, 16B per lane; LDS dst is wave-uniform base + lane*16
#define GLD_LDS16(gp, lp)                                                     \
    __builtin_amdgcn_global_load_lds(                                         \
        (const __attribute__((address_space(1))) void*)(gp),                  \
        (__attribute__((address_space(3))) void*)(lp), 16, 0, 0)

// ---------------- Fused prologue ----------------
// blocks [0,512):   prep — adapted = W + B@A -> bf16, scale = mag/rownorm, 8 rows/block
// blocks [512,8704): cvt — x fp32 -> bf16, 16 elems/thread
__global__ __launch_bounds__(256) void prologue_kernel(
    const float4* __restrict__ x4, unsigned short* __restrict__ xbf,
    const float4* __restrict__ W4,
    const float4* __restrict__ A4,   // [16][1024] float4
    const float* __restrict__ B,     // [4096][16]
    const float* __restrict__ mag,   // [4096]
    unsigned short* __restrict__ wbf,
    float* __restrict__ scale) {
    const int tid = threadIdx.x;
    if (blockIdx.x < 512) {
        const int m0 = blockIdx.x * 8;
        __shared__ float Bs[8][16];
        __shared__ float red[32];
        if (tid < 128) Bs[tid >> 4][tid & 15] = B[m0 * 16 + tid];
        __syncthreads();
        float ss[8] = {};
        for (int c = tid; c < 1024; c += 256) {
            float4 a[16];
#pragma unroll
            for (int r = 0; r < 16; ++r) a[r] = A4[r * 1024 + c];
#pragma unroll
            for (int i = 0; i < 8; ++i) {
                float4 w = W4[(size_t)(m0 + i) * 1024 + c];
#pragma unroll
                for (int r = 0; r < 16; ++r) {
                    const float br = Bs[i][r];
                    w.x += br * a[r].x; w.y += br * a[r].y;
                    w.z += br * a[r].z; w.w += br * a[r].w;
                }
                ss[i] += w.x * w.x + w.y * w.y + w.z * w.z + w.w * w.w;
                us4 o; o[0] = bf_rne(w.x); o[1] = bf_rne(w.y);
                o[2] = bf_rne(w.z); o[3] = bf_rne(w.w);
                *(us4*)&wbf[(size_t)(m0 + i) * 4096 + c * 4] = o;
            }
        }
        const int lane = tid & 63, wv = tid >> 6;
#pragma unroll
        for (int i = 0; i < 8; ++i) {
            float v = ss[i];
#pragma unroll
            for (int off = 32; off > 0; off >>= 1) v += __shfl_down(v, off, 64);
            if (lane == 0) red[wv * 8 + i] = v;
        }
        __syncthreads();
        if (tid < 8) {
            float tot = red[tid] + red[8 + tid] + red[16 + tid] + red[24 + tid];
            scale[m0 + tid] = mag[m0 + tid] / sqrtf(tot);
        }
    } else {
        // cvt: 16 fp32 -> 16 bf16 per thread
        size_t t = (size_t)(blockIdx.x - 512) * 256 + tid;
        float4 a = x4[4 * t], b = x4[4 * t + 1], c = x4[4 * t + 2], d = x4[4 * t + 3];
        us8 o0, o1;
        o0[0] = bf_rne(a.x); o0[1] = bf_rne(a.y); o0[2] = bf_rne(a.z); o0[3] = bf_rne(a.w);
        o0[4] = bf_rne(b.x); o0[5] = bf_rne(b.y); o0[6] = bf_rne(b.z); o0[7] = bf_rne(b.w);
        o1[0] = bf_rne(c.x); o1[1] = bf_rne(c.y); o1[2] = bf_rne(c.z); o1[3] = bf_rne(c.w);
        o1[4] = bf_rne(d.x); o1[5] = bf_rne(d.y); o1[6] = bf_rne(d.z); o1[7] = bf_rne(d.w);
        *(us8*)&xbf[t * 16] = o0;
        *(us8*)&xbf[t * 16 + 8] = o1;
    }
}

// ---------------- GEMM: C[8192][4096] = xbf @ wbf^T * scale ----------------
// 128x128 tile, BK=64, 4 waves in 2x2, each wave 64x64 via 4x4 mfma_f32_16x16x32_bf16
// XOR-swizzled LDS (conflict-free, verified R1: SQ_LDS_BANK_CONFLICT=0)
__global__ __launch_bounds__(256) void dora_gemm(
    const unsigned short* __restrict__ xbf,   // [8192][4096] bf16
    const unsigned short* __restrict__ wbf,   // [4096][4096] bf16
    const float* __restrict__ scale,          // [4096]
    float* __restrict__ out) {                // [8192][4096] fp32
    __shared__ __align__(16) unsigned short As[128 * 64];
    __shared__ __align__(16) unsigned short Bs[128 * 64];

    const int tid  = threadIdx.x;
    const int lane = tid & 63;
    const int w    = tid >> 6;     // wave 0..3
    const int wm   = w >> 1;       // 0..1
    const int wn   = w & 1;        // 0..1
    // XCD-aware swizzle: XCD = blockIdx%8 (round-robin dispatch). Each XCD owns
    // an 8-M-tile stripe and sweeps N fastest -> resident blocks on one XCD
    // share a few xbf rows in its private L2.
    const int xcd = blockIdx.x & 7;
    const int c   = blockIdx.x >> 3;             // 0..255
    const int tileM = (xcd * 8 + (c >> 5)) * 128;
    const int tileN = (c & 31) * 128;

    // staging: group g = rows g*8..g*8+7; lane i -> row g*8+(i>>3), phys chunk (i&7)
    // XOR swizzle: physical 16B chunk p of row holds logical chunk p ^ (row&7)
    const int i8 = lane >> 3;
    const int lc = (lane & 7) ^ i8;

    f32x4 acc[4][4] = {};

    for (int k0 = 0; k0 < 4096; k0 += 64) {
        __syncthreads();
#pragma unroll
        for (int j = 0; j < 4; ++j) {
            const int g   = w * 4 + j;
            const int row = g * 8 + i8;
            GLD_LDS16(xbf + (size_t)(tileM + row) * 4096 + k0 + lc * 8, &As[g * 512]);
            GLD_LDS16(wbf + (size_t)(tileN + row) * 4096 + k0 + lc * 8, &Bs[g * 512]);
        }
        __syncthreads();

        const int q   = lane >> 4;
        const int c15 = lane & 15;
#pragma unroll
        for (int kc = 0; kc < 2; ++kc) {
            s16x8 af[4], bfr[4];
#pragma unroll
            for (int mt = 0; mt < 4; ++mt) {
                const int row  = wm * 64 + mt * 16 + c15;
                const int phys = (kc * 4 + q) ^ (row & 7);
                af[mt] = *(const s16x8*)&As[row * 64 + phys * 8];
            }
#pragma unroll
            for (int nt = 0; nt < 4; ++nt) {
                const int row  = wn * 64 + nt * 16 + c15;
                const int phys = (kc * 4 + q) ^ (row & 7);
                bfr[nt] = *(const s16x8*)&Bs[row * 64 + phys * 8];
            }
#pragma unroll
            for (int mt = 0; mt < 4; ++mt)
#pragma unroll
                for (int nt = 0; nt < 4; ++nt)
                    acc[mt][nt] = __builtin_amdgcn_mfma_f32_16x16x32_bf16(
                        af[mt], bfr[nt], acc[mt][nt], 0, 0, 0);
        }
    }

    // epilogue: C/D layout col=lane&15, row=(lane>>4)*4+reg ; scale by mag/norm
    const int q   = lane >> 4;
    const int c15 = lane & 15;
#pragma unroll
    for (int nt = 0; nt < 4; ++nt) {
        const int col = tileN + wn * 64 + nt * 16 + c15;
        const float s = scale[col];
#pragma unroll
        for (int mt = 0; mt < 4; ++mt) {
            const int row0 = tileM + wm * 64 + mt * 16 + q * 4;
#pragma unroll
            for (int r = 0; r < 4; ++r)
                out[(size_t)(row0 + r) * 4096 + col] = acc[mt][nt][r] * s;
        }
    }
}

extern "C" void kernel_launch(void* const* d_in, const int* in_sizes, int n_in,
                              void* d_out, int out_size, void* d_ws, size_t ws_size,
                              hipStream_t stream) {
    const float* x   = (const float*)d_in[0];   // [4,2048,4096]
    const float* W   = (const float*)d_in[1];   // [4096,4096]
    const float* A   = (const float*)d_in[2];   // [16,4096]
    const float* B   = (const float*)d_in[3];   // [4096,16]
    const float* mag = (const float*)d_in[4];   // [4096]
    float* out = (float*)d_out;

    const size_t XBF_BYTES = (size_t)8192 * 4096 * 2;  // 67,108,864
    const size_t WBF_BYTES = (size_t)4096 * 4096 * 2;  // 33,554,432
    const size_t NEEDED = XBF_BYTES + WBF_BYTES + 4096 * sizeof(float);
    if (ws_size < NEEDED) return;

    unsigned short* xbf = (unsigned short*)d_ws;
    unsigned short* wbf = (unsigned short*)((char*)d_ws + XBF_BYTES);
    float* scale = (float*)((char*)d_ws + XBF_BYTES + WBF_BYTES);

    prologue_kernel<<<8704, 256, 0, stream>>>((const float4*)x, xbf,
                                              (const float4*)W, (const float4*)A,
                                              B, mag, wbf, scale);
    dora_gemm<<<2048, 256, 0, stream>>>(xbf, wbf, scale, out);
}

// Round 3
// 605.094 us; speedup vs baseline: 1.0796x; 1.0796x over previous
//
#include <hip/hip_runtime.h>
#include <hip/hip_bf16.h>
#include <stdint.h>

typedef __attribute__((ext_vector_type(8))) short s16x8;    // bf16 MFMA A/B frag (4 VGPRs)
typedef __attribute__((ext_vector_type(4))) float f32x4;    // MFMA C/D frag
typedef __attribute__((ext_vector_type(8))) unsigned short us8;
typedef __attribute__((ext_vector_type(4))) unsigned short us4;

// ---- bf16 round-to-nearest-even (inputs are finite normals) ----
__device__ inline unsigned short bf_rne(float f) {
    union { float f; uint32_t u; } v; v.f = f;
    uint32_t u = v.u;
    u += 0x7FFFu + ((u >> 16) & 1u);
    return (unsigned short)(u >> 16);
}

// async global->LDS, 16B per lane; LDS dst is wave-uniform base + lane*16
#define GLD_LDS16(gp, lp)                                                     \
    __builtin_amdgcn_global_load_lds(                                         \
        (const __attribute__((address_space(1))) void*)(gp),                  \
        (__attribute__((address_space(3))) void*)(lp), 16, 0, 0)

// ---------------- Fused prologue ----------------
// blocks [0,512):    prep — adapted = W + B@A -> bf16, scale = mag/rownorm, 8 rows/block
// blocks [512,8704): cvt — x fp32 -> bf16, 16 elems/thread, lane-coalesced
__global__ __launch_bounds__(256) void prologue_kernel(
    const float4* __restrict__ x4, us4* __restrict__ xbf4,
    const float4* __restrict__ W4,
    const float4* __restrict__ A4,   // [16][1024] float4
    const float* __restrict__ B,     // [4096][16]
    const float* __restrict__ mag,   // [4096]
    unsigned short* __restrict__ wbf,
    float* __restrict__ scale) {
    const int tid = threadIdx.x;
    if (blockIdx.x < 512) {
        const int m0 = blockIdx.x * 8;
        __shared__ float Bs[8][16];
        __shared__ float red[32];
        if (tid < 128) Bs[tid >> 4][tid & 15] = B[m0 * 16 + tid];
        __syncthreads();
        float ss[8] = {};
        for (int c = tid; c < 1024; c += 256) {
            float4 a[16];
#pragma unroll
            for (int r = 0; r < 16; ++r) a[r] = A4[r * 1024 + c];
#pragma unroll
            for (int i = 0; i < 8; ++i) {
                float4 w = W4[(size_t)(m0 + i) * 1024 + c];
#pragma unroll
                for (int r = 0; r < 16; ++r) {
                    const float br = Bs[i][r];
                    w.x += br * a[r].x; w.y += br * a[r].y;
                    w.z += br * a[r].z; w.w += br * a[r].w;
                }
                ss[i] += w.x * w.x + w.y * w.y + w.z * w.z + w.w * w.w;
                us4 o; o[0] = bf_rne(w.x); o[1] = bf_rne(w.y);
                o[2] = bf_rne(w.z); o[3] = bf_rne(w.w);
                *(us4*)&wbf[(size_t)(m0 + i) * 4096 + c * 4] = o;
            }
        }
        const int lane = tid & 63, wv = tid >> 6;
#pragma unroll
        for (int i = 0; i < 8; ++i) {
            float v = ss[i];
#pragma unroll
            for (int off = 32; off > 0; off >>= 1) v += __shfl_down(v, off, 64);
            if (lane == 0) red[wv * 8 + i] = v;
        }
        __syncthreads();
        if (tid < 8) {
            float tot = red[tid] + red[8 + tid] + red[16 + tid] + red[24 + tid];
            scale[m0 + tid] = mag[m0 + tid] / sqrtf(tot);
        }
    } else {
        // cvt: 4 independent lane-coalesced chains: load float4, store us4 (8B)
        const size_t base = (size_t)(blockIdx.x - 512) * 1024 + tid;
#pragma unroll
        for (int j = 0; j < 4; ++j) {
            const size_t idx = base + j * 256;
            float4 a = x4[idx];
            us4 o;
            o[0] = bf_rne(a.x); o[1] = bf_rne(a.y);
            o[2] = bf_rne(a.z); o[3] = bf_rne(a.w);
            xbf4[idx] = o;
        }
    }
}

// ---------------- GEMM: C[8192][4096] = xbf @ wbf^T * scale ----------------
// 128x128 tile, BK=64, 4 waves in 2x2, each wave 64x64 via 4x4 mfma_f32_16x16x32_bf16
// XOR-swizzled LDS (conflict-free, verified: SQ_LDS_BANK_CONFLICT=0)
// Block mapping: R1's proven ordering (32-block N-sweep per M-tile, FETCH ~335MB)
__global__ __launch_bounds__(256) void dora_gemm(
    const unsigned short* __restrict__ xbf,   // [8192][4096] bf16
    const unsigned short* __restrict__ wbf,   // [4096][4096] bf16
    const float* __restrict__ scale,          // [4096]
    float* __restrict__ out) {                // [8192][4096] fp32
    __shared__ __align__(16) unsigned short As[128 * 64];
    __shared__ __align__(16) unsigned short Bs[128 * 64];

    const int tid  = threadIdx.x;
    const int lane = tid & 63;
    const int w    = tid >> 6;     // wave 0..3
    const int wm   = w >> 1;       // 0..1
    const int wn   = w & 1;        // 0..1
    const int tileM = (blockIdx.x >> 5) * 128;   // 64 M-tiles
    const int tileN = (blockIdx.x & 31) * 128;   // 32 N-tiles

    // staging: group g = rows g*8..g*8+7; lane i -> row g*8+(i>>3), phys chunk (i&7)
    // XOR swizzle: physical 16B chunk p of row holds logical chunk p ^ (row&7)
    const int i8 = lane >> 3;
    const int lc = (lane & 7) ^ i8;

    f32x4 acc[4][4] = {};

    for (int k0 = 0; k0 < 4096; k0 += 64) {
        __syncthreads();
#pragma unroll
        for (int j = 0; j < 4; ++j) {
            const int g   = w * 4 + j;
            const int row = g * 8 + i8;
            GLD_LDS16(xbf + (size_t)(tileM + row) * 4096 + k0 + lc * 8, &As[g * 512]);
            GLD_LDS16(wbf + (size_t)(tileN + row) * 4096 + k0 + lc * 8, &Bs[g * 512]);
        }
        __syncthreads();

        const int q   = lane >> 4;
        const int c15 = lane & 15;
#pragma unroll
        for (int kc = 0; kc < 2; ++kc) {
            s16x8 af[4], bfr[4];
#pragma unroll
            for (int mt = 0; mt < 4; ++mt) {
                const int row  = wm * 64 + mt * 16 + c15;
                const int phys = (kc * 4 + q) ^ (row & 7);
                af[mt] = *(const s16x8*)&As[row * 64 + phys * 8];
            }
#pragma unroll
            for (int nt = 0; nt < 4; ++nt) {
                const int row  = wn * 64 + nt * 16 + c15;
                const int phys = (kc * 4 + q) ^ (row & 7);
                bfr[nt] = *(const s16x8*)&Bs[row * 64 + phys * 8];
            }
#pragma unroll
            for (int mt = 0; mt < 4; ++mt)
#pragma unroll
                for (int nt = 0; nt < 4; ++nt)
                    acc[mt][nt] = __builtin_amdgcn_mfma_f32_16x16x32_bf16(
                        af[mt], bfr[nt], acc[mt][nt], 0, 0, 0);
        }
    }

    // epilogue: C/D layout col=lane&15, row=(lane>>4)*4+reg ; scale by mag/norm
    const int q   = lane >> 4;
    const int c15 = lane & 15;
#pragma unroll
    for (int nt = 0; nt < 4; ++nt) {
        const int col = tileN + wn * 64 + nt * 16 + c15;
        const float s = scale[col];
#pragma unroll
        for (int mt = 0; mt < 4; ++mt) {
            const int row0 = tileM + wm * 64 + mt * 16 + q * 4;
#pragma unroll
            for (int r = 0; r < 4; ++r)
                out[(size_t)(row0 + r) * 4096 + col] = acc[mt][nt][r] * s;
        }
    }
}

extern "C" void kernel_launch(void* const* d_in, const int* in_sizes, int n_in,
                              void* d_out, int out_size, void* d_ws, size_t ws_size,
                              hipStream_t stream) {
    const float* x   = (const float*)d_in[0];   // [4,2048,4096]
    const float* W   = (const float*)d_in[1];   // [4096,4096]
    const float* A   = (const float*)d_in[2];   // [16,4096]
    const float* B   = (const float*)d_in[3];   // [4096,16]
    const float* mag = (const float*)d_in[4];   // [4096]
    float* out = (float*)d_out;

    const size_t XBF_BYTES = (size_t)8192 * 4096 * 2;  // 67,108,864
    const size_t WBF_BYTES = (size_t)4096 * 4096 * 2;  // 33,554,432
    const size_t NEEDED = XBF_BYTES + WBF_BYTES + 4096 * sizeof(float);
    if (ws_size < NEEDED) return;

    unsigned short* xbf = (unsigned short*)d_ws;
    unsigned short* wbf = (unsigned short*)((char*)d_ws + XBF_BYTES);
    float* scale = (float*)((char*)d_ws + XBF_BYTES + WBF_BYTES);

    prologue_kernel<<<8704, 256, 0, stream>>>((const float4*)x, (us4*)xbf,
                                              (const float4*)W, (const float4*)A,
                                              B, mag, wbf, scale);
    dora_gemm<<<2048, 256, 0, stream>>>(xbf, wbf, scale, out);
}